// Round 12
// baseline (848.450 us; speedup 1.0000x reference)
//
#include <hip/hip_runtime.h>
#include <math.h>

#define VOL   128
#define V2    (VOL*VOL)
#define V3    (VOL*VOL*VOL)
#define NPTS  262144
#define LATD  16
#define BATCH 8
#define FACTORF 64.0f
#define NBINS (128*128)

// ws layout (bytes): [0,256) hbuf | [256,...) hist | binstart | cursor | perm
#define WS_HBUF   0
#define WS_HIST   256
#define WS_START  (WS_HIST + NBINS*4)
#define WS_CURSOR (WS_START + NBINS*4)
#define WS_PERM   (WS_CURSOR + NBINS*4)
#define WS_NEEDED (WS_PERM + NPTS*4)

// Round-to-nearest-even float -> bf16 -> float (ml_dtypes / XLA bf16 RNE)
__device__ __forceinline__ float bf16r(float x) {
    unsigned u = __float_as_uint(x);
    u = (u + 0x7fffu + ((u >> 16) & 1u)) & 0xffff0000u;
    return __uint_as_float(u);
}

// SIREN MLP, per-op bf16 (XLA/ml_dtypes semantics). Verified round 11.
__global__ void mlp_kernel(const float* __restrict__ x,
                           const float* __restrict__ W0,
                           const float* __restrict__ b0,
                           const float* __restrict__ Wh,
                           const float* __restrict__ bh,
                           float* __restrict__ hout) {
    int b = threadIdx.x;
    if (b >= BATCH) return;
    float xb[LATD];
    #pragma unroll
    for (int i = 0; i < LATD; ++i) xb[i] = bf16r(x[b*LATD + i]);
    float h[8];
    #pragma unroll
    for (int j = 0; j < 8; ++j) {
        float acc = 0.f;
        #pragma unroll
        for (int i = 0; i < LATD; ++i) acc += xb[i] * bf16r(W0[i*8 + j]);
        float t = bf16r(acc);
        t = bf16r(t + bf16r(b0[j]));
        t = bf16r(30.0f * t);
        h[j] = bf16r(sinf(t));
    }
    for (int l = 0; l < 4; ++l) {
        float nh[8];
        #pragma unroll
        for (int j = 0; j < 8; ++j) {
            float acc = 0.f;
            #pragma unroll
            for (int r = 0; r < 8; ++r) acc += h[r] * bf16r(Wh[(l*8 + r)*8 + j]);
            float t = bf16r(acc);
            t = bf16r(t + bf16r(bh[l*8 + j]));
            float s = bf16r(sinf(t));
            nh[j] = bf16r(h[j] + s);
        }
        #pragma unroll
        for (int j = 0; j < 8; ++j) h[j] = nh[j];
    }
    #pragma unroll
    for (int j = 0; j < 8; ++j) hout[b*8 + j] = h[j];
}

__device__ __forceinline__ int bin_key(const int* inds, int n) {
    // address-order key: z-major then y (grid addr = z*V2 + y*VOL + x)
    return inds[n*3 + 0] * VOL + inds[n*3 + 1];
}

__global__ __launch_bounds__(256) void hist_kernel(const int* __restrict__ inds,
                                                   unsigned* __restrict__ hist) {
    int n = blockIdx.x * blockDim.x + threadIdx.x;
    if (n >= NPTS) return;
    atomicAdd(&hist[bin_key(inds, n)], 1u);
}

// Single-block exclusive scan over NBINS (=16384) histogram entries.
__global__ __launch_bounds__(256) void scan_kernel(const unsigned* __restrict__ hist,
                                                   unsigned* __restrict__ binstart,
                                                   unsigned* __restrict__ cursor) {
    __shared__ unsigned part[256];
    int t = threadIdx.x;
    const int CH = NBINS / 256;   // 64
    unsigned s = 0;
    for (int k = 0; k < CH; ++k) s += hist[t*CH + k];
    part[t] = s; __syncthreads();
    for (int off = 1; off < 256; off <<= 1) {
        unsigned v = (t >= off) ? part[t - off] : 0u;
        __syncthreads();
        part[t] += v;
        __syncthreads();
    }
    unsigned run = (t == 0) ? 0u : part[t - 1];
    for (int k = 0; k < CH; ++k) {
        int idx = t*CH + k;
        binstart[idx] = run;
        cursor[idx]   = run;
        run += hist[idx];
    }
}

__global__ __launch_bounds__(256) void permute_kernel(const int* __restrict__ inds,
                                                      unsigned* __restrict__ cursor,
                                                      unsigned* __restrict__ perm) {
    int n = blockIdx.x * blockDim.x + threadIdx.x;
    if (n >= NPTS) return;
    unsigned pos = atomicAdd(&cursor[bin_key(inds, n)], 1u);
    perm[pos] = n;
}

// Thread = (point, batch). Points processed in bin-sorted order so concurrent
// atomics target a small, L2-resident address window per grid.
__global__ __launch_bounds__(256) void scatter_kernel(
    const float* __restrict__ Wf, const float* __restrict__ bfv_g,
    const float* __restrict__ rv, const int* __restrict__ inds,
    const float* __restrict__ hbuf, const unsigned* __restrict__ perm,
    float* __restrict__ out)
{
    __shared__ float hs[BATCH*8];
    if (threadIdx.x < BATCH*8) hs[threadIdx.x] = hbuf[threadIdx.x];
    __syncthreads();

    long long tid = (long long)blockIdx.x * blockDim.x + threadIdx.x;
    int pid = (int)(tid >> 3);
    int b   = (int)(tid & 7);
    if (pid >= NPTS) return;
    int n = perm[pid];

    int iz = inds[n*3 + 0], iy = inds[n*3 + 1], ix = inds[n*3 + 2];
    float cnx = ((float)ix - FACTORF) / FACTORF;
    float cny = ((float)iy - FACTORF) / FACTORF;
    float cnz = ((float)iz - FACTORF) / FACTORF;
    float val0 = rv[n];
    float4 bfv = ((const float4*)bfv_g)[n];

    float o0 = bfv.x, o1 = bfv.y, o2 = bfv.z, o3 = bfv.w;
    #pragma unroll
    for (int r = 0; r < 8; ++r) {
        float4 w4 = ((const float4*)(Wf + (size_t)r * 4 * NPTS))[n];
        float hv = hs[b*8 + r];
        o0 = fmaf(hv, w4.x, o0);
        o1 = fmaf(hv, w4.y, o1);
        o2 = fmaf(hv, w4.z, o2);
        o3 = fmaf(hv, w4.w, o3);
    }
    float cx = FACTORF * (cnx + o0) + FACTORF;
    float cy = FACTORF * (cny + o1) + FACTORF;
    float cz = FACTORF * (cnz + o2) + FACTORF;
    float val = val0 + o3;

    float fxf = floorf(cx), fyf = floorf(cy), fzf = floorf(cz);
    int bx = (int)fxf, by = (int)fyf, bz = (int)fzf;
    float fx = cx - fxf, fy = cy - fyf, fz = cz - fzf;
    float gx = 1.f - fx, gy = 1.f - fy, gz = 1.f - fz;

    float w[8] = {gx*gy*gz, fx*gy*gz, gx*fy*gz, gx*gy*fz,
                  gx*fy*fz, fx*gy*fz, fx*fy*gz, fx*fy*fz};
    static const int offs[8][3] = {{0,0,0},{1,0,0},{0,1,0},{0,0,1},
                                   {0,1,1},{1,0,1},{1,1,0},{1,1,1}};

    float* ob = out + (size_t)b * V3;
    #pragma unroll
    for (int o = 0; o < 8; ++o) {
        int X = (bx + offs[o][0]) & (VOL-1);
        int Y = (by + offs[o][1]) & (VOL-1);
        int Z = (bz + offs[o][2]) & (VOL-1);
        atomicAdd(ob + (size_t)Z*V2 + Y*VOL + X, val * w[o]);
    }
}

// Fallback (round-11 verified path) if workspace is too small for binning.
__global__ __launch_bounds__(256) void scatter_fallback(
    const float* __restrict__ Wf, const float* __restrict__ bfv_g,
    const float* __restrict__ rv, const int* __restrict__ inds,
    const float* __restrict__ hbuf, float* __restrict__ out)
{
    __shared__ float hs[BATCH*8];
    if (threadIdx.x < BATCH*8) hs[threadIdx.x] = hbuf[threadIdx.x];
    __syncthreads();
    int n = blockIdx.x * blockDim.x + threadIdx.x;
    if (n >= NPTS) return;
    int iz = inds[n*3 + 0], iy = inds[n*3 + 1], ix = inds[n*3 + 2];
    float cnx = ((float)ix - FACTORF) / FACTORF;
    float cny = ((float)iy - FACTORF) / FACTORF;
    float cnz = ((float)iz - FACTORF) / FACTORF;
    float val0 = rv[n];
    float4 bfv = ((const float4*)bfv_g)[n];
    float4 wf[8];
    #pragma unroll
    for (int r = 0; r < 8; ++r)
        wf[r] = ((const float4*)(Wf + (size_t)r * 4 * NPTS))[n];
    static const int offs[8][3] = {{0,0,0},{1,0,0},{0,1,0},{0,0,1},
                                   {0,1,1},{1,0,1},{1,1,0},{1,1,1}};
    #pragma unroll
    for (int b = 0; b < BATCH; ++b) {
        float o0 = bfv.x, o1 = bfv.y, o2 = bfv.z, o3 = bfv.w;
        #pragma unroll
        for (int r = 0; r < 8; ++r) {
            float hv = hs[b*8 + r];
            o0 = fmaf(hv, wf[r].x, o0);
            o1 = fmaf(hv, wf[r].y, o1);
            o2 = fmaf(hv, wf[r].z, o2);
            o3 = fmaf(hv, wf[r].w, o3);
        }
        float cx = FACTORF * (cnx + o0) + FACTORF;
        float cy = FACTORF * (cny + o1) + FACTORF;
        float cz = FACTORF * (cnz + o2) + FACTORF;
        float val = val0 + o3;
        float fxf = floorf(cx), fyf = floorf(cy), fzf = floorf(cz);
        int bx = (int)fxf, by = (int)fyf, bz = (int)fzf;
        float fx = cx - fxf, fy = cy - fyf, fz = cz - fzf;
        float gx = 1.f - fx, gy = 1.f - fy, gz = 1.f - fz;
        float w[8] = {gx*gy*gz, fx*gy*gz, gx*fy*gz, gx*gy*fz,
                      gx*fy*fz, fx*gy*fz, fx*fy*gz, fx*fy*fz};
        float* ob = out + (size_t)b * V3;
        #pragma unroll
        for (int o = 0; o < 8; ++o) {
            int X = (bx + offs[o][0]) & (VOL-1);
            int Y = (by + offs[o][1]) & (VOL-1);
            int Z = (bz + offs[o][2]) & (VOL-1);
            atomicAdd(ob + (size_t)Z*V2 + Y*VOL + X, val * w[o]);
        }
    }
}

extern "C" void kernel_launch(void* const* d_in, const int* in_sizes, int n_in,
                              void* d_out, int out_size, void* d_ws, size_t ws_size,
                              hipStream_t stream) {
    const float* x    = (const float*)d_in[0];
    const float* W0   = (const float*)d_in[1];
    const float* b0   = (const float*)d_in[2];
    const float* Wh   = (const float*)d_in[3];
    const float* bh   = (const float*)d_in[4];
    const float* Wf   = (const float*)d_in[5];
    const float* bf   = (const float*)d_in[6];
    const float* rv   = (const float*)d_in[7];
    const int*   inds = (const int*)d_in[8];
    float* out = (float*)d_out;
    char*  ws  = (char*)d_ws;

    float*    hbuf     = (float*)(ws + WS_HBUF);
    unsigned* hist     = (unsigned*)(ws + WS_HIST);
    unsigned* binstart = (unsigned*)(ws + WS_START);
    unsigned* cursor   = (unsigned*)(ws + WS_CURSOR);
    unsigned* perm     = (unsigned*)(ws + WS_PERM);

    hipMemsetAsync(d_out, 0, (size_t)out_size * sizeof(float), stream);
    mlp_kernel<<<1, 64, 0, stream>>>(x, W0, b0, Wh, bh, hbuf);

    if (ws_size >= (size_t)WS_NEEDED) {
        hipMemsetAsync(hist, 0, NBINS*4, stream);
        hist_kernel<<<NPTS/256, 256, 0, stream>>>(inds, hist);
        scan_kernel<<<1, 256, 0, stream>>>(hist, binstart, cursor);
        permute_kernel<<<NPTS/256, 256, 0, stream>>>(inds, cursor, perm);
        scatter_kernel<<<(NPTS*BATCH)/256, 256, 0, stream>>>(
            Wf, bf, rv, inds, hbuf, perm, out);
    } else {
        scatter_fallback<<<NPTS/256, 256, 0, stream>>>(Wf, bf, rv, inds, hbuf, out);
    }
}

// Round 13
// 194.541 us; speedup vs baseline: 4.3613x; 4.3613x over previous
//
#include <hip/hip_runtime.h>
#include <math.h>

#define VOL   128
#define V2    (VOL*VOL)
#define V3    (VOL*VOL*VOL)
#define NPTS  262144
#define LATD  16
#define BATCH 8
#define FACTORF 64.0f
#define NBINS (VOL*VOL)
#define RZ 8
#define RY 8
#define NREG 256
#define FAR_CAP 8192

// ws layout (bytes)
#define WS_HBUF    0u
#define WS_HIST    256u        // NBINS*4 = 65536
#define WS_START   65792u      // (NBINS+1)*4 -> pad to 131584
#define WS_CURSOR  131584u     // NBINS*4
#define WS_RANK    197120u     // NPTS*4
#define WS_KEYS    1245696u    // NPTS*4
#define WS_FARCNT  2294272u    // 256
#define WS_FARLIST 2294528u    // FAR_CAP*4
#define WS_COORDS  2327296u    // NPTS*BATCH*16
#define WS_FULL    35881728u

// Round-to-nearest-even float -> bf16 -> float (ml_dtypes / XLA bf16 RNE)
__device__ __forceinline__ float bf16r(float x) {
    unsigned u = __float_as_uint(x);
    u = (u + 0x7fffu + ((u >> 16) & 1u)) & 0xffff0000u;
    return __uint_as_float(u);
}

// SIREN MLP, per-op bf16 (verified round 11).
__global__ void mlp_kernel(const float* __restrict__ x,
                           const float* __restrict__ W0,
                           const float* __restrict__ b0,
                           const float* __restrict__ Wh,
                           const float* __restrict__ bh,
                           float* __restrict__ hout) {
    int b = threadIdx.x;
    if (b >= BATCH) return;
    float xb[LATD];
    #pragma unroll
    for (int i = 0; i < LATD; ++i) xb[i] = bf16r(x[b*LATD + i]);
    float h[8];
    #pragma unroll
    for (int j = 0; j < 8; ++j) {
        float acc = 0.f;
        #pragma unroll
        for (int i = 0; i < LATD; ++i) acc += xb[i] * bf16r(W0[i*8 + j]);
        float t = bf16r(acc);
        t = bf16r(t + bf16r(b0[j]));
        t = bf16r(30.0f * t);
        h[j] = bf16r(sinf(t));
    }
    for (int l = 0; l < 4; ++l) {
        float nh[8];
        #pragma unroll
        for (int j = 0; j < 8; ++j) {
            float acc = 0.f;
            #pragma unroll
            for (int r = 0; r < 8; ++r) acc += h[r] * bf16r(Wh[(l*8 + r)*8 + j]);
            float t = bf16r(acc);
            t = bf16r(t + bf16r(bh[l*8 + j]));
            float s = bf16r(sinf(t));
            nh[j] = bf16r(h[j] + s);
        }
        #pragma unroll
        for (int j = 0; j < 8; ++j) h[j] = nh[j];
    }
    #pragma unroll
    for (int j = 0; j < 8; ++j) hout[b*8 + j] = h[j];
}

__global__ __launch_bounds__(256) void hist_kernel(const int* __restrict__ inds,
                                                   unsigned* __restrict__ hist) {
    int n = blockIdx.x * 256 + threadIdx.x;
    if (n >= NPTS) return;
    atomicAdd(&hist[inds[n*3]*VOL + inds[n*3+1]], 1u);
}

__global__ __launch_bounds__(256) void scan_kernel(const unsigned* __restrict__ hist,
                                                   unsigned* __restrict__ binstart,
                                                   unsigned* __restrict__ cursor) {
    __shared__ unsigned part[256];
    int t = threadIdx.x;
    const int CH = NBINS / 256;
    unsigned s = 0;
    for (int k = 0; k < CH; ++k) s += hist[t*CH + k];
    part[t] = s; __syncthreads();
    for (int off = 1; off < 256; off <<= 1) {
        unsigned v = (t >= off) ? part[t - off] : 0u;
        __syncthreads();
        part[t] += v;
        __syncthreads();
    }
    unsigned run = (t == 0) ? 0u : part[t - 1];
    for (int k = 0; k < CH; ++k) {
        int idx = t*CH + k;
        binstart[idx] = run;
        cursor[idx]   = run;
        run += hist[idx];
    }
    if (t == 255) binstart[NBINS] = NPTS;
}

__global__ __launch_bounds__(256) void rank_kernel(const int* __restrict__ inds,
                                                   unsigned* __restrict__ cursor,
                                                   unsigned* __restrict__ rank) {
    int n = blockIdx.x * 256 + threadIdx.x;
    if (n >= NPTS) return;
    rank[n] = atomicAdd(&cursor[inds[n*3]*VOL + inds[n*3+1]], 1u);
}

// Per point: compute (cx,cy,cz,val) for all 8 batches, store in bin-sorted order.
__global__ __launch_bounds__(256) void coords_kernel(
    const float* __restrict__ Wf, const float* __restrict__ bfv_g,
    const float* __restrict__ rv, const int* __restrict__ inds,
    const float* __restrict__ hbuf, const unsigned* __restrict__ rank,
    float4* __restrict__ coords_s, unsigned* __restrict__ keys)
{
    __shared__ float hs[64];
    if (threadIdx.x < 64) hs[threadIdx.x] = hbuf[threadIdx.x];
    __syncthreads();
    int n = blockIdx.x * 256 + threadIdx.x;
    if (n >= NPTS) return;
    int iz = inds[n*3], iy = inds[n*3+1], ix = inds[n*3+2];
    float cnx = ((float)ix - FACTORF) / FACTORF;
    float cny = ((float)iy - FACTORF) / FACTORF;
    float cnz = ((float)iz - FACTORF) / FACTORF;
    float val0 = rv[n];
    float4 bfv = ((const float4*)bfv_g)[n];
    float4 wf[8];
    #pragma unroll
    for (int r = 0; r < 8; ++r)
        wf[r] = ((const float4*)(Wf + (size_t)r * 4 * NPTS))[n];
    unsigned pos = rank[n];
    keys[pos] = (unsigned)((iz << 7) | iy);
    #pragma unroll
    for (int b = 0; b < BATCH; ++b) {
        float o0 = bfv.x, o1 = bfv.y, o2 = bfv.z, o3 = bfv.w;
        #pragma unroll
        for (int r = 0; r < 8; ++r) {
            float hv = hs[b*8 + r];
            o0 = fmaf(hv, wf[r].x, o0);
            o1 = fmaf(hv, wf[r].y, o1);
            o2 = fmaf(hv, wf[r].z, o2);
            o3 = fmaf(hv, wf[r].w, o3);
        }
        float4 c;
        c.x = FACTORF * (cnx + o0) + FACTORF;
        c.y = FACTORF * (cny + o1) + FACTORF;
        c.z = FACTORF * (cnz + o2) + FACTORF;
        c.w = val0 + o3;
        coords_s[(size_t)b * NPTS + pos] = c;
    }
}

// One workgroup = (batch, 8z x 8y x 128x region). LDS-accumulate, plain store.
__global__ __launch_bounds__(256) void region_kernel(
    const float4* __restrict__ coords_s, const unsigned* __restrict__ keys,
    const unsigned* __restrict__ binstart,
    unsigned* __restrict__ farcnt, unsigned* __restrict__ farlist,
    float* __restrict__ out)
{
    __shared__ float tile[RZ*RY*VOL];
    int tid = threadIdx.x;
    int b   = blockIdx.x >> 8;
    int rid = blockIdx.x & 255;
    int z0 = (rid >> 4) * RZ, y0 = (rid & 15) * RY;
    for (int i = tid; i < RZ*RY*VOL; i += 256) tile[i] = 0.f;
    __syncthreads();

    int ylo = y0 - 3, yhi = y0 + RY + 2;
    int sA0, sA1, sB0, sB1;
    if (ylo < 0)        { sA0 = ylo + VOL; sA1 = VOL; sB0 = 0; sB1 = yhi; }
    else if (yhi > VOL) { sA0 = ylo; sA1 = VOL; sB0 = 0; sB1 = yhi - VOL; }
    else                { sA0 = ylo; sA1 = yhi; sB0 = 0; sB1 = 0; }

    const float4* cb = coords_s + (size_t)b * NPTS;
    const int ox[8] = {0,1,0,0,0,1,1,1};
    const int oy[8] = {0,0,1,0,1,0,1,1};
    const int oz[8] = {0,0,0,1,1,1,0,1};

    for (int zr = z0 - 3; zr < z0 + RZ + 2; ++zr) {
        int zz = (zr + VOL) & (VOL-1);
        int base = zz * VOL;
        for (int sg = 0; sg < 2; ++sg) {
            int a  = sg ? sB0 : sA0;
            int e2 = sg ? sB1 : sA1;
            if (a >= e2) continue;
            unsigned s = binstart[base + a];
            unsigned e = binstart[base + e2];
            for (unsigned i = s + tid; i < e; i += 256) {
                unsigned kv = keys[i];
                int piz = kv >> 7, piy = kv & 127;
                float4 c = cb[i];
                float fxf = floorf(c.x), fyf = floorf(c.y), fzf = floorf(c.z);
                int bx = (int)fxf, by = (int)fyf, bz = (int)fzf;
                bool near = ((unsigned)(bz - piz + 2) <= 4u) &&
                            ((unsigned)(by - piy + 2) <= 4u);
                if (near) {
                    float fx = c.x - fxf, fy = c.y - fyf, fz = c.z - fzf;
                    float gx = 1.f - fx, gy = 1.f - fy, gz = 1.f - fz;
                    float val = c.w;
                    float w[8] = {gx*gy*gz, fx*gy*gz, gx*fy*gz, gx*gy*fz,
                                  gx*fy*fz, fx*gy*fz, fx*fy*gz, fx*fy*fz};
                    #pragma unroll
                    for (int o = 0; o < 8; ++o) {
                        int Z = (bz + oz[o]) & 127;
                        int Y = (by + oy[o]) & 127;
                        int X = (bx + ox[o]) & 127;
                        int dz = Z - z0, dy = Y - y0;
                        if ((unsigned)dz < RZ && (unsigned)dy < RY)
                            atomicAdd(&tile[(dz << 10) + (dy << 7) + X], val * w[o]);
                    }
                } else if (piz >= z0 && piz < z0+RZ && piy >= y0 && piy < y0+RY) {
                    unsigned pos = atomicAdd(farcnt, 1u);
                    if (pos < FAR_CAP) farlist[pos] = (i << 3) | (unsigned)b;
                }
            }
        }
    }
    __syncthreads();
    size_t ob = (size_t)b * V3;
    for (int i = tid; i < RZ*RY*VOL; i += 256) {
        int lz = i >> 10, rem = i & 1023, ly = rem >> 7, lx = rem & 127;
        out[ob + (size_t)(z0+lz)*V2 + (y0+ly)*VOL + lx] = tile[i];
    }
}

// Cleanup for far-displaced point-batches (expected ~0-10).
__global__ __launch_bounds__(256) void far_kernel(
    const float4* __restrict__ coords_s,
    const unsigned* __restrict__ farcnt, const unsigned* __restrict__ farlist,
    float* __restrict__ out)
{
    unsigned cnt = *farcnt;
    if (cnt > FAR_CAP) cnt = FAR_CAP;
    const int ox[8] = {0,1,0,0,0,1,1,1};
    const int oy[8] = {0,0,1,0,1,0,1,1};
    const int oz[8] = {0,0,0,1,1,1,0,1};
    for (unsigned idx = blockIdx.x * 256 + threadIdx.x; idx < cnt;
         idx += gridDim.x * 256) {
        unsigned e = farlist[idx];
        unsigned pid = e >> 3;
        int b = (int)(e & 7u);
        float4 c = coords_s[(size_t)b * NPTS + pid];
        float fxf = floorf(c.x), fyf = floorf(c.y), fzf = floorf(c.z);
        int bx = (int)fxf, by = (int)fyf, bz = (int)fzf;
        float fx = c.x - fxf, fy = c.y - fyf, fz = c.z - fzf;
        float gx = 1.f - fx, gy = 1.f - fy, gz = 1.f - fz;
        float val = c.w;
        float w[8] = {gx*gy*gz, fx*gy*gz, gx*fy*gz, gx*gy*fz,
                      gx*fy*fz, fx*gy*fz, fx*fy*gz, fx*fy*fz};
        float* ob = out + (size_t)b * V3;
        #pragma unroll
        for (int o = 0; o < 8; ++o) {
            int Z = (bz + oz[o]) & 127;
            int Y = (by + oy[o]) & 127;
            int X = (bx + ox[o]) & 127;
            atomicAdd(ob + (size_t)Z*V2 + Y*VOL + X, val * w[o]);
        }
    }
}

// Fallback (round-11 verified path) if workspace too small.
__global__ __launch_bounds__(256) void scatter_fallback(
    const float* __restrict__ Wf, const float* __restrict__ bfv_g,
    const float* __restrict__ rv, const int* __restrict__ inds,
    const float* __restrict__ hbuf, float* __restrict__ out)
{
    __shared__ float hs[BATCH*8];
    if (threadIdx.x < BATCH*8) hs[threadIdx.x] = hbuf[threadIdx.x];
    __syncthreads();
    int n = blockIdx.x * blockDim.x + threadIdx.x;
    if (n >= NPTS) return;
    int iz = inds[n*3 + 0], iy = inds[n*3 + 1], ix = inds[n*3 + 2];
    float cnx = ((float)ix - FACTORF) / FACTORF;
    float cny = ((float)iy - FACTORF) / FACTORF;
    float cnz = ((float)iz - FACTORF) / FACTORF;
    float val0 = rv[n];
    float4 bfv = ((const float4*)bfv_g)[n];
    float4 wf[8];
    #pragma unroll
    for (int r = 0; r < 8; ++r)
        wf[r] = ((const float4*)(Wf + (size_t)r * 4 * NPTS))[n];
    static const int offs[8][3] = {{0,0,0},{1,0,0},{0,1,0},{0,0,1},
                                   {0,1,1},{1,0,1},{1,1,0},{1,1,1}};
    #pragma unroll
    for (int b = 0; b < BATCH; ++b) {
        float o0 = bfv.x, o1 = bfv.y, o2 = bfv.z, o3 = bfv.w;
        #pragma unroll
        for (int r = 0; r < 8; ++r) {
            float hv = hs[b*8 + r];
            o0 = fmaf(hv, wf[r].x, o0);
            o1 = fmaf(hv, wf[r].y, o1);
            o2 = fmaf(hv, wf[r].z, o2);
            o3 = fmaf(hv, wf[r].w, o3);
        }
        float cx = FACTORF * (cnx + o0) + FACTORF;
        float cy = FACTORF * (cny + o1) + FACTORF;
        float cz = FACTORF * (cnz + o2) + FACTORF;
        float val = val0 + o3;
        float fxf = floorf(cx), fyf = floorf(cy), fzf = floorf(cz);
        int bx = (int)fxf, by = (int)fyf, bz = (int)fzf;
        float fx = cx - fxf, fy = cy - fyf, fz = cz - fzf;
        float gx = 1.f - fx, gy = 1.f - fy, gz = 1.f - fz;
        float w[8] = {gx*gy*gz, fx*gy*gz, gx*fy*gz, gx*gy*fz,
                      gx*fy*fz, fx*gy*fz, fx*fy*gz, fx*fy*fz};
        float* ob = out + (size_t)b * V3;
        #pragma unroll
        for (int o = 0; o < 8; ++o) {
            int X = (bx + offs[o][0]) & (VOL-1);
            int Y = (by + offs[o][1]) & (VOL-1);
            int Z = (bz + offs[o][2]) & (VOL-1);
            atomicAdd(ob + (size_t)Z*V2 + Y*VOL + X, val * w[o]);
        }
    }
}

extern "C" void kernel_launch(void* const* d_in, const int* in_sizes, int n_in,
                              void* d_out, int out_size, void* d_ws, size_t ws_size,
                              hipStream_t stream) {
    const float* x    = (const float*)d_in[0];
    const float* W0   = (const float*)d_in[1];
    const float* b0   = (const float*)d_in[2];
    const float* Wh   = (const float*)d_in[3];
    const float* bh   = (const float*)d_in[4];
    const float* Wf   = (const float*)d_in[5];
    const float* bf   = (const float*)d_in[6];
    const float* rv   = (const float*)d_in[7];
    const int*   inds = (const int*)d_in[8];
    float* out = (float*)d_out;
    char*  ws  = (char*)d_ws;

    float*    hbuf     = (float*)(ws + WS_HBUF);
    unsigned* hist     = (unsigned*)(ws + WS_HIST);
    unsigned* binstart = (unsigned*)(ws + WS_START);
    unsigned* cursor   = (unsigned*)(ws + WS_CURSOR);
    unsigned* rank     = (unsigned*)(ws + WS_RANK);
    unsigned* keys     = (unsigned*)(ws + WS_KEYS);
    unsigned* farcnt   = (unsigned*)(ws + WS_FARCNT);
    unsigned* farlist  = (unsigned*)(ws + WS_FARLIST);
    float4*   coords_s = (float4*)(ws + WS_COORDS);

    mlp_kernel<<<1, 64, 0, stream>>>(x, W0, b0, Wh, bh, hbuf);

    if (ws_size >= (size_t)WS_FULL) {
        hipMemsetAsync(hist, 0, NBINS*4, stream);
        hipMemsetAsync(farcnt, 0, 4, stream);
        hist_kernel<<<NPTS/256, 256, 0, stream>>>(inds, hist);
        scan_kernel<<<1, 256, 0, stream>>>(hist, binstart, cursor);
        rank_kernel<<<NPTS/256, 256, 0, stream>>>(inds, cursor, rank);
        coords_kernel<<<NPTS/256, 256, 0, stream>>>(Wf, bf, rv, inds, hbuf,
                                                    rank, coords_s, keys);
        region_kernel<<<NREG*BATCH, 256, 0, stream>>>(coords_s, keys, binstart,
                                                      farcnt, farlist, out);
        far_kernel<<<8, 256, 0, stream>>>(coords_s, farcnt, farlist, out);
    } else {
        hipMemsetAsync(d_out, 0, (size_t)out_size * sizeof(float), stream);
        scatter_fallback<<<NPTS/256, 256, 0, stream>>>(Wf, bf, rv, inds, hbuf, out);
    }
}